// Round 1
// baseline (3371.751 us; speedup 1.0000x reference)
//
#include <hip/hip_runtime.h>
#include <math.h>

#define E_EDGES 8192
#define D_FEAT 2048
#define K2 4096   // 2*D
#define H_DIM 128
#define N_NODES 100000
#define SIM_TH 0.7f

// ---------------------------------------------------------------------------
// Kernel 1: cosine similarity per edge. One wave (64 lanes) per edge.
// ---------------------------------------------------------------------------
__global__ __launch_bounds__(256) void sim_kernel(const float* __restrict__ xf,
                                                  const float* __restrict__ yf,
                                                  float* __restrict__ sim) {
    int gid  = blockIdx.x * blockDim.x + threadIdx.x;
    int wave = gid >> 6;
    int lane = threadIdx.x & 63;
    if (wave >= E_EDGES) return;
    const float4* xp = (const float4*)(xf + (size_t)wave * D_FEAT);
    const float4* yp = (const float4*)(yf + (size_t)wave * D_FEAT);
    float dot = 0.f, xx = 0.f, yy = 0.f;
#pragma unroll
    for (int j = 0; j < 8; ++j) {            // 512 float4 per row / 64 lanes
        float4 a = xp[lane + j * 64];
        float4 b = yp[lane + j * 64];
        dot += a.x * b.x + a.y * b.y + a.z * b.z + a.w * b.w;
        xx  += a.x * a.x + a.y * a.y + a.z * a.z + a.w * a.w;
        yy  += b.x * b.x + b.y * b.y + b.z * b.z + b.w * b.w;
    }
#pragma unroll
    for (int off = 32; off; off >>= 1) {
        dot += __shfl_xor(dot, off);
        xx  += __shfl_xor(xx, off);
        yy  += __shfl_xor(yy, off);
    }
    if (lane == 0) {
        float nx = fmaxf(sqrtf(xx), 1e-8f);
        float ny = fmaxf(sqrtf(yy), 1e-8f);
        sim[wave] = dot / (nx * ny);
    }
}

// ---------------------------------------------------------------------------
// Kernel 2: fused gate MLP.  C[e][n] = relu(concat(x,y)[e] . W1[n] + b1[n]),
// then attn[e] = sigmoid(sum_n C[e][n]*W2[n] + b2), w[e] = mask ? attn : 0.
// fp32 GEMM: M=8192 (edges), N=128 (H), K=4096.  BM=32, BN=128, BK=32.
// Thread block 256: thread t -> te=t>>5 (4 edges te*4..+3), tn=t&31 (4 n's).
// LDS tiles XOR-swizzled to keep float4 alignment + spread banks.
// ---------------------------------------------------------------------------
#define BM 32
#define BK 32
#define SWZ(r, c) ((c) ^ ((((r) >> 2) & 7) << 2))

__global__ __launch_bounds__(256) void gate_kernel(
        const float* __restrict__ xf, const float* __restrict__ yf,
        const float* __restrict__ W1, const float* __restrict__ b1,
        const float* __restrict__ W2, const float* __restrict__ b2,
        const float* __restrict__ sim, float* __restrict__ wout) {
    __shared__ float As[BM][BK];
    __shared__ float Bs[H_DIM][BK];
    __shared__ float red[BM][33];

    int t  = threadIdx.x;
    int e0 = blockIdx.x * BM;
    int te = t >> 5;        // 0..7
    int tn = t & 31;        // 0..31
    int n0 = tn * 4;

    float acc[4][4] = {};

    for (int k0 = 0; k0 < K2; k0 += BK) {
        const float* src = (k0 < D_FEAT) ? xf : yf;
        int kk0 = (k0 < D_FEAT) ? k0 : (k0 - D_FEAT);
        // --- stage A tile: 32 rows x 32 k, one float4 per thread
        {
            int row = t >> 3;
            int c   = (t & 7) * 4;
            float4 v = *(const float4*)(src + (size_t)(e0 + row) * D_FEAT + kk0 + c);
            *(float4*)(&As[row][SWZ(row, c)]) = v;
        }
        // --- stage B tile: 128 rows x 32 k, four float4 per thread
#pragma unroll
        for (int r = 0; r < 4; ++r) {
            int n = (t >> 3) + r * 32;
            int c = (t & 7) * 4;
            float4 v = *(const float4*)(W1 + (size_t)n * K2 + k0 + c);
            *(float4*)(&Bs[n][SWZ(n, c)]) = v;
        }
        __syncthreads();
        // --- compute
        int swzA = (te & 7) << 2;
        int swzB = (tn & 7) << 2;
#pragma unroll
        for (int kk = 0; kk < BK; kk += 4) {
            float4 av[4], bv[4];
#pragma unroll
            for (int i = 0; i < 4; ++i)
                av[i] = *(const float4*)(&As[te * 4 + i][kk ^ swzA]);
#pragma unroll
            for (int j = 0; j < 4; ++j)
                bv[j] = *(const float4*)(&Bs[n0 + j][kk ^ swzB]);
#pragma unroll
            for (int i = 0; i < 4; ++i)
#pragma unroll
                for (int j = 0; j < 4; ++j)
                    acc[i][j] += av[i].x * bv[j].x + av[i].y * bv[j].y +
                                 av[i].z * bv[j].z + av[i].w * bv[j].w;
        }
        __syncthreads();
    }

    // --- epilogue: bias + relu + second layer partial per thread
    float b1v[4], w2v[4];
#pragma unroll
    for (int j = 0; j < 4; ++j) { b1v[j] = b1[n0 + j]; w2v[j] = W2[n0 + j]; }
#pragma unroll
    for (int i = 0; i < 4; ++i) {
        float p = 0.f;
#pragma unroll
        for (int j = 0; j < 4; ++j) {
            float h = fmaxf(acc[i][j] + b1v[j], 0.f);
            p += h * w2v[j];
        }
        red[te * 4 + i][tn] = p;
    }
    __syncthreads();
    if (t < BM) {
        float s = 0.f;
#pragma unroll
        for (int c = 0; c < 32; ++c) s += red[t][c];
        float logit = s + b2[0];
        float attn  = 1.f / (1.f + expf(-logit));
        float sv    = sim[e0 + t];
        wout[e0 + t] = (sv >= SIM_TH) ? attn : 0.f;
    }
}

// ---------------------------------------------------------------------------
// Kernel 3: copy parent/rank inputs into workspace (inputs must not mutate).
// ---------------------------------------------------------------------------
__global__ void init_kernel(const int* __restrict__ pin, const float* __restrict__ rin,
                            int* __restrict__ p, float* __restrict__ r) {
    int i = blockIdx.x * blockDim.x + threadIdx.x;
    if (i < N_NODES) { p[i] = pin[i]; r[i] = rin[i]; }
}

// ---------------------------------------------------------------------------
// Kernel 4: the sequential union-find scan (must exactly replicate reference
// order + path compression).  Single thread.
// ---------------------------------------------------------------------------
__global__ void uf_kernel(const int* __restrict__ x_idx, const int* __restrict__ y_idx,
                          const float* __restrict__ w, const float* __restrict__ sim,
                          int* __restrict__ parent, float* __restrict__ rank) {
    if (threadIdx.x != 0 || blockIdx.x != 0) return;
    for (int i = 0; i < E_EDGES; ++i) {
        float s = sim[i];
        if (s >= SIM_TH) {
            float wi = w[i];
            int x = x_idx[i], y = y_idx[i];
            // find root of x with full path compression (matches reference)
            int rx = x, p;
            while ((p = parent[rx]) != rx) rx = p;
            int j = x;
            while (j != rx) { int nj = parent[j]; parent[j] = rx; j = nj; }
            // find root of y on the updated forest
            int ry = y;
            while ((p = parent[ry]) != ry) ry = p;
            j = y;
            while (j != ry) { int nj = parent[j]; parent[j] = ry; j = nj; }
            if (rx != ry) {
                float rkx = rank[rx], rky = rank[ry];
                bool bx   = rkx > rky;
                int big   = bx ? rx : ry;
                int small = bx ? ry : rx;
                parent[small] = big;
                rank[big] = (bx ? rkx : rky) + (bx ? rky : rkx) * wi;
            }
            // rx == ry: reference sets parent[big]=big (no-op) and adds 0.0
        }
    }
}

// ---------------------------------------------------------------------------
// Kernel 5: emit parent (as float) and rank into d_out.
// ---------------------------------------------------------------------------
__global__ void final_kernel(const int* __restrict__ p, const float* __restrict__ r,
                             float* __restrict__ pout, float* __restrict__ rout) {
    int i = blockIdx.x * blockDim.x + threadIdx.x;
    if (i < N_NODES) { pout[i] = (float)p[i]; rout[i] = r[i]; }
}

// ---------------------------------------------------------------------------
extern "C" void kernel_launch(void* const* d_in, const int* in_sizes, int n_in,
                              void* d_out, int out_size, void* d_ws, size_t ws_size,
                              hipStream_t stream) {
    const int*   x_idx = (const int*)d_in[0];
    const int*   y_idx = (const int*)d_in[1];
    const float* xf    = (const float*)d_in[2];
    const float* yf    = (const float*)d_in[3];
    const float* W1    = (const float*)d_in[4];
    const float* b1    = (const float*)d_in[5];
    const float* W2    = (const float*)d_in[6];
    const float* b2    = (const float*)d_in[7];
    const int*   pin   = (const int*)d_in[8];
    const float* rin   = (const float*)d_in[9];

    float* out      = (float*)d_out;
    float* w_out    = out;                       // [E]
    float* pout     = out + E_EDGES;             // [N] (float-encoded ints)
    float* rout     = out + E_EDGES + N_NODES;   // [N]

    float* wsf      = (float*)d_ws;
    float* sim_ws   = wsf;                       // [E]
    int*   p_ws     = (int*)(wsf + E_EDGES);     // [N]
    float* r_ws     = wsf + E_EDGES + N_NODES;   // [N]

    // 1) cosine sim (one wave per edge)
    sim_kernel<<<(E_EDGES * 64) / 256, 256, 0, stream>>>(xf, yf, sim_ws);
    // 2) gate MLP -> w
    gate_kernel<<<E_EDGES / BM, 256, 0, stream>>>(xf, yf, W1, b1, W2, b2, sim_ws, w_out);
    // 3) copy parent/rank into workspace
    init_kernel<<<(N_NODES + 255) / 256, 256, 0, stream>>>(pin, rin, p_ws, r_ws);
    // 4) sequential union-find
    uf_kernel<<<1, 64, 0, stream>>>(x_idx, y_idx, w_out, sim_ws, p_ws, r_ws);
    // 5) emit parent/rank
    final_kernel<<<(N_NODES + 255) / 256, 256, 0, stream>>>(p_ws, r_ws, pout, rout);
}

// Round 2
// 1820.024 us; speedup vs baseline: 1.8526x; 1.8526x over previous
//
#include <hip/hip_runtime.h>
#include <math.h>

#define E_EDGES 8192
#define D_FEAT 2048
#define K2 4096   // 2*D
#define H_DIM 128
#define N_NODES 100000
#define SIM_TH 0.7f
#define NSLOTS (2 * E_EDGES)   // 16384 compact slots

// ---------------------------------------------------------------------------
// Kernel 1: cosine similarity per edge. One wave (64 lanes) per edge.
// ---------------------------------------------------------------------------
__global__ __launch_bounds__(256) void sim_kernel(const float* __restrict__ xf,
                                                  const float* __restrict__ yf,
                                                  float* __restrict__ sim) {
    int gid  = blockIdx.x * blockDim.x + threadIdx.x;
    int wave = gid >> 6;
    int lane = threadIdx.x & 63;
    if (wave >= E_EDGES) return;
    const float4* xp = (const float4*)(xf + (size_t)wave * D_FEAT);
    const float4* yp = (const float4*)(yf + (size_t)wave * D_FEAT);
    float dot = 0.f, xx = 0.f, yy = 0.f;
#pragma unroll
    for (int j = 0; j < 8; ++j) {
        float4 a = xp[lane + j * 64];
        float4 b = yp[lane + j * 64];
        dot += a.x * b.x + a.y * b.y + a.z * b.z + a.w * b.w;
        xx  += a.x * a.x + a.y * a.y + a.z * a.z + a.w * a.w;
        yy  += b.x * b.x + b.y * b.y + b.z * b.z + b.w * b.w;
    }
#pragma unroll
    for (int off = 32; off; off >>= 1) {
        dot += __shfl_xor(dot, off);
        xx  += __shfl_xor(xx, off);
        yy  += __shfl_xor(yy, off);
    }
    if (lane == 0) {
        float nx = fmaxf(sqrtf(xx), 1e-8f);
        float ny = fmaxf(sqrtf(yy), 1e-8f);
        sim[wave] = dot / (nx * ny);
    }
}

// ---------------------------------------------------------------------------
// Kernel 2: fused gate MLP (fp32, vector-ALU GEMM M=8192 N=128 K=4096).
// ---------------------------------------------------------------------------
#define BM 32
#define BK 32
#define SWZ(r, c) ((c) ^ ((((r) >> 2) & 7) << 2))

__global__ __launch_bounds__(256) void gate_kernel(
        const float* __restrict__ xf, const float* __restrict__ yf,
        const float* __restrict__ W1, const float* __restrict__ b1,
        const float* __restrict__ W2, const float* __restrict__ b2,
        const float* __restrict__ sim, float* __restrict__ wout) {
    __shared__ float As[BM][BK];
    __shared__ float Bs[H_DIM][BK];
    __shared__ float red[BM][33];

    int t  = threadIdx.x;
    int e0 = blockIdx.x * BM;
    int te = t >> 5;
    int tn = t & 31;
    int n0 = tn * 4;

    float acc[4][4] = {};

    for (int k0 = 0; k0 < K2; k0 += BK) {
        const float* src = (k0 < D_FEAT) ? xf : yf;
        int kk0 = (k0 < D_FEAT) ? k0 : (k0 - D_FEAT);
        {
            int row = t >> 3;
            int c   = (t & 7) * 4;
            float4 v = *(const float4*)(src + (size_t)(e0 + row) * D_FEAT + kk0 + c);
            *(float4*)(&As[row][SWZ(row, c)]) = v;
        }
#pragma unroll
        for (int r = 0; r < 4; ++r) {
            int n = (t >> 3) + r * 32;
            int c = (t & 7) * 4;
            float4 v = *(const float4*)(W1 + (size_t)n * K2 + k0 + c);
            *(float4*)(&Bs[n][SWZ(n, c)]) = v;
        }
        __syncthreads();
        int swzA = (te & 7) << 2;
        int swzB = (tn & 7) << 2;
#pragma unroll
        for (int kk = 0; kk < BK; kk += 4) {
            float4 av[4], bv[4];
#pragma unroll
            for (int i = 0; i < 4; ++i)
                av[i] = *(const float4*)(&As[te * 4 + i][kk ^ swzA]);
#pragma unroll
            for (int j = 0; j < 4; ++j)
                bv[j] = *(const float4*)(&Bs[n0 + j][kk ^ swzB]);
#pragma unroll
            for (int i = 0; i < 4; ++i)
#pragma unroll
                for (int j = 0; j < 4; ++j)
                    acc[i][j] += av[i].x * bv[j].x + av[i].y * bv[j].y +
                                 av[i].z * bv[j].z + av[i].w * bv[j].w;
        }
        __syncthreads();
    }

    float b1v[4], w2v[4];
#pragma unroll
    for (int j = 0; j < 4; ++j) { b1v[j] = b1[n0 + j]; w2v[j] = W2[n0 + j]; }
#pragma unroll
    for (int i = 0; i < 4; ++i) {
        float p = 0.f;
#pragma unroll
        for (int j = 0; j < 4; ++j) {
            float h = fmaxf(acc[i][j] + b1v[j], 0.f);
            p += h * w2v[j];
        }
        red[te * 4 + i][tn] = p;
    }
    __syncthreads();
    if (t < BM) {
        float s = 0.f;
#pragma unroll
        for (int c = 0; c < 32; ++c) s += red[t][c];
        float logit = s + b2[0];
        float attn  = 1.f / (1.f + expf(-logit));
        float sv    = sim[e0 + t];
        wout[e0 + t] = (sv >= SIM_TH) ? attn : 0.f;
    }
}

// ---------------------------------------------------------------------------
// Kernel 3: init firstocc (=INT_MAX) and orig (=-1).
// ---------------------------------------------------------------------------
__global__ void initmap_kernel(int* __restrict__ fo, int* __restrict__ orig) {
    int i = blockIdx.x * blockDim.x + threadIdx.x;
    if (i < N_NODES) fo[i] = 0x7FFFFFFF;
    if (i < NSLOTS)  orig[i] = -1;
}

// ---------------------------------------------------------------------------
// Kernel 4: claim compact slot = first occurrence index in sequence
//           x0,y0,x1,y1,...  (atomicMin is deterministic)
// ---------------------------------------------------------------------------
__global__ void claim_kernel(const int* __restrict__ x_idx, const int* __restrict__ y_idx,
                             int* __restrict__ fo) {
    int i = blockIdx.x * blockDim.x + threadIdx.x;
    if (i >= NSLOTS) return;
    int e = i >> 1;
    int v = (i & 1) ? y_idx[e] : x_idx[e];
    atomicMin(&fo[v], i);
}

// ---------------------------------------------------------------------------
// Kernel 5: scatter orig[slot] = node for claimed slots.
// ---------------------------------------------------------------------------
__global__ void orig_kernel(const int* __restrict__ x_idx, const int* __restrict__ y_idx,
                            const int* __restrict__ fo, int* __restrict__ orig) {
    int i = blockIdx.x * blockDim.x + threadIdx.x;
    if (i >= NSLOTS) return;
    int e = i >> 1;
    int v = (i & 1) ? y_idx[e] : x_idx[e];
    if (fo[v] == i) orig[i] = v;
}

// ---------------------------------------------------------------------------
// Kernel 6: compact masked edges (order-preserving) into int4 records
//           {cx, cy, w_bits, 0}. Single block, 256 threads, 32 edges each.
// ---------------------------------------------------------------------------
__global__ __launch_bounds__(256) void compact_kernel(
        const int* __restrict__ x_idx, const int* __restrict__ y_idx,
        const int* __restrict__ fo, const float* __restrict__ sim,
        const float* __restrict__ w, int4* __restrict__ rec, int* __restrict__ nmask) {
    __shared__ int partial[256];
    int t = threadIdx.x;
    int cnt = 0;
    for (int j = 0; j < 32; ++j) {
        int e = t * 32 + j;
        cnt += (sim[e] >= SIM_TH) ? 1 : 0;
    }
    partial[t] = cnt;
    __syncthreads();
    // Kogge-Stone inclusive scan
    for (int off = 1; off < 256; off <<= 1) {
        int mine  = partial[t];
        int other = (t >= off) ? partial[t - off] : 0;
        __syncthreads();
        partial[t] = mine + other;
        __syncthreads();
    }
    int pos = partial[t] - cnt;   // exclusive prefix
    if (t == 255) *nmask = partial[255];
    for (int j = 0; j < 32; ++j) {
        int e = t * 32 + j;
        if (sim[e] >= SIM_TH) {
            int4 r;
            r.x = fo[x_idx[e]];
            r.y = fo[y_idx[e]];
            r.z = __float_as_int(w[e]);
            r.w = 0;
            rec[pos++] = r;
        }
    }
}

// ---------------------------------------------------------------------------
// Kernel 7: serial union-find, entire state in LDS (128 KB dynamic).
// ---------------------------------------------------------------------------
__global__ __launch_bounds__(256) void uf_kernel(
        const int4* __restrict__ rec, const int* __restrict__ nmask,
        const int* __restrict__ orig, const float* __restrict__ rin,
        int* __restrict__ gpar, float* __restrict__ grank) {
    extern __shared__ int smem[];
    int*   lp = smem;                     // [NSLOTS]
    float* lr = (float*)(smem + NSLOTS);  // [NSLOTS]
    int t = threadIdx.x;
    for (int c = t; c < NSLOTS; c += 256) {
        lp[c] = c;                        // input parent == arange
        int o = orig[c];
        lr[c] = (o >= 0) ? rin[o] : 1.0f;
    }
    __syncthreads();
    if (t == 0) {
        int n = *nmask;
        if (n > 0) {
            int4 e = rec[0];
            for (int i = 0; i < n; ++i) {
                int4 enext = rec[i + 1];          // prefetch (rec has E+1 slots)
                int x = e.x, y = e.y;
                float wi = __int_as_float(e.z);
                // find root of x
                int rx = x, p;
                while ((p = lp[rx]) != rx) rx = p;
                // compress x's path (skip writes that wouldn't change state)
                int j = x;
                while ((p = lp[j]) != rx) { lp[j] = rx; j = p; }
                // find root of y on updated forest
                int ry = y;
                while ((p = lp[ry]) != ry) ry = p;
                j = y;
                while ((p = lp[j]) != ry) { lp[j] = ry; j = p; }
                if (rx != ry) {
                    float a = lr[rx], b = lr[ry];
                    bool bx = a > b;
                    int big = bx ? rx : ry, small = bx ? ry : rx;
                    lp[small] = big;
                    lr[big]   = bx ? (a + b * wi) : (b + a * wi);
                }
                e = enext;
            }
        }
    }
    __syncthreads();
    for (int c = t; c < NSLOTS; c += 256) { gpar[c] = lp[c]; grank[c] = lr[c]; }
}

// ---------------------------------------------------------------------------
// Kernel 8: base output = copy inputs (untouched nodes stay as-is).
// ---------------------------------------------------------------------------
__global__ void base_kernel(const int* __restrict__ pin, const float* __restrict__ rin,
                            float* __restrict__ pout, float* __restrict__ rout) {
    int i = blockIdx.x * blockDim.x + threadIdx.x;
    if (i < N_NODES) { pout[i] = (float)pin[i]; rout[i] = rin[i]; }
}

// ---------------------------------------------------------------------------
// Kernel 9: scatter compact results back to original node ids.
// ---------------------------------------------------------------------------
__global__ void scatter_kernel(const int* __restrict__ orig, const int* __restrict__ gpar,
                               const float* __restrict__ grank,
                               float* __restrict__ pout, float* __restrict__ rout) {
    int c = blockIdx.x * blockDim.x + threadIdx.x;
    if (c >= NSLOTS) return;
    int o = orig[c];
    if (o >= 0) {
        pout[o] = (float)orig[gpar[c]];
        rout[o] = grank[c];
    }
}

// ---------------------------------------------------------------------------
extern "C" void kernel_launch(void* const* d_in, const int* in_sizes, int n_in,
                              void* d_out, int out_size, void* d_ws, size_t ws_size,
                              hipStream_t stream) {
    const int*   x_idx = (const int*)d_in[0];
    const int*   y_idx = (const int*)d_in[1];
    const float* xf    = (const float*)d_in[2];
    const float* yf    = (const float*)d_in[3];
    const float* W1    = (const float*)d_in[4];
    const float* b1    = (const float*)d_in[5];
    const float* W2    = (const float*)d_in[6];
    const float* b2    = (const float*)d_in[7];
    const int*   pin   = (const int*)d_in[8];
    const float* rin   = (const float*)d_in[9];

    float* out   = (float*)d_out;
    float* w_out = out;                        // [E]
    float* pout  = out + E_EDGES;              // [N]
    float* rout  = out + E_EDGES + N_NODES;    // [N]

    char* ws = (char*)d_ws;
    float* sim_ws = (float*)(ws + 0);          //  32768 B
    int*   fo     = (int*)  (ws + 32768);      // 400000 B
    int*   orig   = (int*)  (ws + 432768);     //  65536 B
    int4*  rec    = (int4*) (ws + 498304);     // 131088 B (E+1 records)
    int*   nmask  = (int*)  (ws + 629392);     //     16 B
    int*   gpar   = (int*)  (ws + 629408);     //  65536 B
    float* grank  = (float*)(ws + 694944);     //  65536 B  -> total 760480 B

    // 1) cosine sim
    sim_kernel<<<(E_EDGES * 64) / 256, 256, 0, stream>>>(xf, yf, sim_ws);
    // 2) gate MLP -> w (output 0)
    gate_kernel<<<E_EDGES / BM, 256, 0, stream>>>(xf, yf, W1, b1, W2, b2, sim_ws, w_out);
    // 3) compact-id mapping
    int g = (N_NODES + 255) / 256;
    initmap_kernel<<<g, 256, 0, stream>>>(fo, orig);
    claim_kernel<<<NSLOTS / 256, 256, 0, stream>>>(x_idx, y_idx, fo);
    orig_kernel<<<NSLOTS / 256, 256, 0, stream>>>(x_idx, y_idx, fo, orig);
    // 4) masked-edge compaction
    compact_kernel<<<1, 256, 0, stream>>>(x_idx, y_idx, fo, sim_ws, w_out, rec, nmask);
    // 5) serial union-find in LDS
    uf_kernel<<<1, 256, 2 * NSLOTS * sizeof(int), stream>>>(rec, nmask, orig, rin, gpar, grank);
    // 6) emit outputs
    base_kernel<<<g, 256, 0, stream>>>(pin, rin, pout, rout);
    scatter_kernel<<<NSLOTS / 256, 256, 0, stream>>>(orig, gpar, grank, pout, rout);
}

// Round 3
// 1338.133 us; speedup vs baseline: 2.5197x; 1.3601x over previous
//
#include <hip/hip_runtime.h>
#include <math.h>

#define E_EDGES 8192
#define D_FEAT 2048
#define K2 4096   // 2*D
#define H_DIM 128
#define N_NODES 100000
#define SIM_TH 0.7f
#define NSLOTS (2 * E_EDGES)   // 16384 compact slots
#define PATH_MAX 4096

// ---------------------------------------------------------------------------
// Kernel 1: cosine similarity per edge. One wave (64 lanes) per edge.
// ---------------------------------------------------------------------------
__global__ __launch_bounds__(256) void sim_kernel(const float* __restrict__ xf,
                                                  const float* __restrict__ yf,
                                                  float* __restrict__ sim) {
    int gid  = blockIdx.x * blockDim.x + threadIdx.x;
    int wave = gid >> 6;
    int lane = threadIdx.x & 63;
    if (wave >= E_EDGES) return;
    const float4* xp = (const float4*)(xf + (size_t)wave * D_FEAT);
    const float4* yp = (const float4*)(yf + (size_t)wave * D_FEAT);
    float dot = 0.f, xx = 0.f, yy = 0.f;
#pragma unroll
    for (int j = 0; j < 8; ++j) {
        float4 a = xp[lane + j * 64];
        float4 b = yp[lane + j * 64];
        dot += a.x * b.x + a.y * b.y + a.z * b.z + a.w * b.w;
        xx  += a.x * a.x + a.y * a.y + a.z * a.z + a.w * a.w;
        yy  += b.x * b.x + b.y * b.y + b.z * b.z + b.w * b.w;
    }
#pragma unroll
    for (int off = 32; off; off >>= 1) {
        dot += __shfl_xor(dot, off);
        xx  += __shfl_xor(xx, off);
        yy  += __shfl_xor(yy, off);
    }
    if (lane == 0) {
        float nx = fmaxf(sqrtf(xx), 1e-8f);
        float ny = fmaxf(sqrtf(yy), 1e-8f);
        sim[wave] = dot / (nx * ny);
    }
}

// ---------------------------------------------------------------------------
// Kernel 2: init fo (=INT_MAX), orig (=-1), and zero w output.
// ---------------------------------------------------------------------------
__global__ void initmap_kernel(int* __restrict__ fo, int* __restrict__ orig,
                               float* __restrict__ wout) {
    int i = blockIdx.x * blockDim.x + threadIdx.x;
    if (i < N_NODES) fo[i] = 0x7FFFFFFF;
    if (i < NSLOTS)  orig[i] = -1;
    if (i < E_EDGES) wout[i] = 0.f;
}

// ---------------------------------------------------------------------------
// Kernel 3: claim compact slot = first occurrence index in x0,y0,x1,y1,...
// ---------------------------------------------------------------------------
__global__ void claim_kernel(const int* __restrict__ x_idx, const int* __restrict__ y_idx,
                             int* __restrict__ fo) {
    int i = blockIdx.x * blockDim.x + threadIdx.x;
    if (i >= NSLOTS) return;
    int e = i >> 1;
    int v = (i & 1) ? y_idx[e] : x_idx[e];
    atomicMin(&fo[v], i);
}

// ---------------------------------------------------------------------------
// Kernel 4: orig[slot] = node for claimed slots.
// ---------------------------------------------------------------------------
__global__ void orig_kernel(const int* __restrict__ x_idx, const int* __restrict__ y_idx,
                            const int* __restrict__ fo, int* __restrict__ orig) {
    int i = blockIdx.x * blockDim.x + threadIdx.x;
    if (i >= NSLOTS) return;
    int e = i >> 1;
    int v = (i & 1) ? y_idx[e] : x_idx[e];
    if (fo[v] == i) orig[i] = v;
}

// ---------------------------------------------------------------------------
// Kernel 5: order-preserving compaction of masked edges into records
//           rec = {cx, cy, eidx, (w filled later by gate)}.
// ---------------------------------------------------------------------------
__global__ __launch_bounds__(256) void maskscan_kernel(
        const int* __restrict__ x_idx, const int* __restrict__ y_idx,
        const int* __restrict__ fo, const float* __restrict__ sim,
        int4* __restrict__ rec, int* __restrict__ nmask) {
    __shared__ int partial[256];
    int t = threadIdx.x;
    int cnt = 0;
    for (int j = 0; j < 32; ++j) {
        int e = t * 32 + j;
        cnt += (sim[e] >= SIM_TH) ? 1 : 0;
    }
    partial[t] = cnt;
    __syncthreads();
    for (int off = 1; off < 256; off <<= 1) {
        int mine  = partial[t];
        int other = (t >= off) ? partial[t - off] : 0;
        __syncthreads();
        partial[t] = mine + other;
        __syncthreads();
    }
    int pos = partial[t] - cnt;
    if (t == 255) *nmask = partial[255];
    for (int j = 0; j < 32; ++j) {
        int e = t * 32 + j;
        if (sim[e] >= SIM_TH) {
            int4 r;
            r.x = fo[x_idx[e]];
            r.y = fo[y_idx[e]];
            r.z = e;
            r.w = 0;
            rec[pos++] = r;
        }
    }
}

// ---------------------------------------------------------------------------
// Kernel 6: gate MLP over MASKED edges only (gathered rows).
// fp32 GEMM: M=nmask, N=128, K=4096. BM=32 edges/block, early-exit blocks.
// Writes w_out[eidx] and rec[i].w (float bits).
// ---------------------------------------------------------------------------
#define BM 32
#define BK 32
#define SWZ(r, c) ((c) ^ ((((r) >> 2) & 7) << 2))

__global__ __launch_bounds__(256) void gate_kernel(
        const float* __restrict__ xf, const float* __restrict__ yf,
        const float* __restrict__ W1, const float* __restrict__ b1,
        const float* __restrict__ W2, const float* __restrict__ b2,
        int4* __restrict__ rec, const int* __restrict__ nmask,
        float* __restrict__ wout) {
    __shared__ float As[BM][BK];
    __shared__ float Bs[H_DIM][BK];
    __shared__ float red[BM][33];
    __shared__ int   elds[BM];

    int n  = *nmask;
    int b0 = blockIdx.x * BM;
    if (b0 >= n) return;

    int t  = threadIdx.x;
    if (t < BM) {
        int idx = b0 + t;
        elds[t] = (idx < n) ? rec[idx].z : rec[b0].z;
    }
    __syncthreads();

    int te = t >> 5;
    int tn = t & 31;
    int n0 = tn * 4;

    float acc[4][4] = {};

    for (int k0 = 0; k0 < K2; k0 += BK) {
        const float* src = (k0 < D_FEAT) ? xf : yf;
        int kk0 = (k0 < D_FEAT) ? k0 : (k0 - D_FEAT);
        {
            int row = t >> 3;
            int c   = (t & 7) * 4;
            float4 v = *(const float4*)(src + (size_t)elds[row] * D_FEAT + kk0 + c);
            *(float4*)(&As[row][SWZ(row, c)]) = v;
        }
#pragma unroll
        for (int r = 0; r < 4; ++r) {
            int nn = (t >> 3) + r * 32;
            int c  = (t & 7) * 4;
            float4 v = *(const float4*)(W1 + (size_t)nn * K2 + k0 + c);
            *(float4*)(&Bs[nn][SWZ(nn, c)]) = v;
        }
        __syncthreads();
        int swzA = (te & 7) << 2;
        int swzB = (tn & 7) << 2;
#pragma unroll
        for (int kk = 0; kk < BK; kk += 4) {
            float4 av[4], bv[4];
#pragma unroll
            for (int i = 0; i < 4; ++i)
                av[i] = *(const float4*)(&As[te * 4 + i][kk ^ swzA]);
#pragma unroll
            for (int j = 0; j < 4; ++j)
                bv[j] = *(const float4*)(&Bs[n0 + j][kk ^ swzB]);
#pragma unroll
            for (int i = 0; i < 4; ++i)
#pragma unroll
                for (int j = 0; j < 4; ++j)
                    acc[i][j] += av[i].x * bv[j].x + av[i].y * bv[j].y +
                                 av[i].z * bv[j].z + av[i].w * bv[j].w;
        }
        __syncthreads();
    }

    float b1v[4], w2v[4];
#pragma unroll
    for (int j = 0; j < 4; ++j) { b1v[j] = b1[n0 + j]; w2v[j] = W2[n0 + j]; }
#pragma unroll
    for (int i = 0; i < 4; ++i) {
        float p = 0.f;
#pragma unroll
        for (int j = 0; j < 4; ++j) {
            float h = fmaxf(acc[i][j] + b1v[j], 0.f);
            p += h * w2v[j];
        }
        red[te * 4 + i][tn] = p;
    }
    __syncthreads();
    if (t < BM && b0 + t < n) {
        float s = 0.f;
#pragma unroll
        for (int c = 0; c < 32; ++c) s += red[t][c];
        float logit = s + b2[0];
        float attn  = 1.f / (1.f + expf(-logit));
        wout[elds[t]] = attn;
        ((int*)&rec[b0 + t])[3] = __float_as_int(attn);
    }
}

// ---------------------------------------------------------------------------
// Kernel 7: serial union-find in LDS.
//   parent u16 [16384] 32KB | rank f32 [16384] 64KB | path scratch 2x16KB.
//   Dual-chain interleaved find + speculative rank reads + scratch compression.
// ---------------------------------------------------------------------------
__global__ __launch_bounds__(256) void uf_kernel(
        const int4* __restrict__ rec, const int* __restrict__ nmask,
        const int* __restrict__ orig, const float* __restrict__ rin,
        int* __restrict__ gpar, float* __restrict__ grank) {
    extern __shared__ char smem[];
    unsigned short* lp = (unsigned short*)smem;            // 32 KB
    float* lr    = (float*)(smem + 32768);                 // 64 KB
    int*   pathx = (int*)  (smem + 32768 + 65536);         // 16 KB
    int*   pathy = (int*)  (smem + 32768 + 65536 + 16384); // 16 KB

    int t = threadIdx.x;
    for (int c = t; c < NSLOTS; c += 256) {
        lp[c] = (unsigned short)c;          // input parent == arange
        int o = orig[c];
        lr[c] = (o >= 0) ? rin[o] : 1.0f;
    }
    __syncthreads();
    if (t == 0) {
        int n = *nmask;
        if (n > 0) {
            int4 e0 = rec[0];
            int4 e1 = rec[1];
            for (int i = 0; i < n; ++i) {
                int4 e2 = rec[i + 2];       // prefetch (rec has E+4 slots)
                int x = e0.x, y = e0.y;
                float wi = __int_as_float(e0.w);

                // --- dual-chain find with speculative rank reads
                int rx = x, ry = y;
                int nx = lp[rx], ny = lp[ry];
                float rax = lr[rx], ray = lr[ry];
                int cntx = 0, cnty = 0;
                while (nx != rx || ny != ry) {
                    if (nx != rx) {
                        if (cntx < PATH_MAX) pathx[cntx] = rx;
                        cntx++; rx = nx;
                    }
                    if (ny != ry) {
                        if (cnty < PATH_MAX) pathy[cnty] = ry;
                        cnty++; ry = ny;
                    }
                    nx = lp[rx]; ny = lp[ry];     // parallel pair
                    rax = lr[rx]; ray = lr[ry];   // speculative, same level
                }

                // --- compression: independent reads of recorded path
                for (int d = 0; d < cntx; ++d) lp[pathx[d]] = (unsigned short)rx;
                for (int d = 0; d < cnty; ++d) lp[pathy[d]] = (unsigned short)ry;

                // --- union
                if (rx != ry) {
                    bool bx = rax > ray;
                    int big = bx ? rx : ry, small = bx ? ry : rx;
                    lp[small] = (unsigned short)big;
                    lr[big]   = bx ? (rax + ray * wi) : (ray + rax * wi);
                }
                e0 = e1; e1 = e2;
            }
        }
    }
    __syncthreads();
    for (int c = t; c < NSLOTS; c += 256) { gpar[c] = lp[c]; grank[c] = lr[c]; }
}

// ---------------------------------------------------------------------------
// Kernel 8: base output = copy inputs.
// ---------------------------------------------------------------------------
__global__ void base_kernel(const int* __restrict__ pin, const float* __restrict__ rin,
                            float* __restrict__ pout, float* __restrict__ rout) {
    int i = blockIdx.x * blockDim.x + threadIdx.x;
    if (i < N_NODES) { pout[i] = (float)pin[i]; rout[i] = rin[i]; }
}

// ---------------------------------------------------------------------------
// Kernel 9: scatter compact results back to original ids.
// ---------------------------------------------------------------------------
__global__ void scatter_kernel(const int* __restrict__ orig, const int* __restrict__ gpar,
                               const float* __restrict__ grank,
                               float* __restrict__ pout, float* __restrict__ rout) {
    int c = blockIdx.x * blockDim.x + threadIdx.x;
    if (c >= NSLOTS) return;
    int o = orig[c];
    if (o >= 0) {
        pout[o] = (float)orig[gpar[c]];
        rout[o] = grank[c];
    }
}

// ---------------------------------------------------------------------------
extern "C" void kernel_launch(void* const* d_in, const int* in_sizes, int n_in,
                              void* d_out, int out_size, void* d_ws, size_t ws_size,
                              hipStream_t stream) {
    const int*   x_idx = (const int*)d_in[0];
    const int*   y_idx = (const int*)d_in[1];
    const float* xf    = (const float*)d_in[2];
    const float* yf    = (const float*)d_in[3];
    const float* W1    = (const float*)d_in[4];
    const float* b1    = (const float*)d_in[5];
    const float* W2    = (const float*)d_in[6];
    const float* b2    = (const float*)d_in[7];
    const int*   pin   = (const int*)d_in[8];
    const float* rin   = (const float*)d_in[9];

    float* out   = (float*)d_out;
    float* w_out = out;                        // [E]
    float* pout  = out + E_EDGES;              // [N]
    float* rout  = out + E_EDGES + N_NODES;    // [N]

    char* ws = (char*)d_ws;
    float* sim_ws = (float*)(ws + 0);          //  32768 B
    int*   fo     = (int*)  (ws + 32768);      // 400000 B
    int*   orig   = (int*)  (ws + 432768);     //  65536 B
    int4*  rec    = (int4*) (ws + 498304);     // (E+4)*16 = 131136 B
    int*   nmask  = (int*)  (ws + 629440);     //     64 B
    int*   gpar   = (int*)  (ws + 629504);     //  65536 B
    float* grank  = (float*)(ws + 695040);     //  65536 B -> total 760576 B

    // 1) cosine sim
    sim_kernel<<<(E_EDGES * 64) / 256, 256, 0, stream>>>(xf, yf, sim_ws);
    // 2) compact-id mapping + zero w
    int g = (N_NODES + 255) / 256;
    initmap_kernel<<<g, 256, 0, stream>>>(fo, orig, w_out);
    claim_kernel<<<NSLOTS / 256, 256, 0, stream>>>(x_idx, y_idx, fo);
    orig_kernel<<<NSLOTS / 256, 256, 0, stream>>>(x_idx, y_idx, fo, orig);
    // 3) masked-edge compaction (records)
    maskscan_kernel<<<1, 256, 0, stream>>>(x_idx, y_idx, fo, sim_ws, rec, nmask);
    // 4) gate MLP over masked edges only
    gate_kernel<<<E_EDGES / BM, 256, 0, stream>>>(xf, yf, W1, b1, W2, b2, rec, nmask, w_out);
    // 5) serial union-find in LDS
    uf_kernel<<<1, 256, 131072, stream>>>(rec, nmask, orig, rin, gpar, grank);
    // 6) emit outputs
    base_kernel<<<g, 256, 0, stream>>>(pin, rin, pout, rout);
    scatter_kernel<<<NSLOTS / 256, 256, 0, stream>>>(orig, gpar, grank, pout, rout);
}